// Round 12
// baseline (454.689 us; speedup 1.0000x reference)
//
#include <hip/hip_runtime.h>
#include <math.h>

#define NB 16
#define NCIN 64
#define NCOUT 64
#define NH 256
#define NW 256
#define NM 64          // 2*M1 row modes
#define NKX 32         // M2 retained columns
#define INV256 (1.0f/256.0f)

typedef __attribute__((ext_vector_type(8))) short short8v;
typedef __attribute__((ext_vector_type(4))) float f32x4;
typedef unsigned short u16;
typedef unsigned int u32;

__device__ __forceinline__ void bf16_split(float v, u16& hi, u16& lo) {
    u32 b = __float_as_uint(v);
    u32 hib = b & 0xffff0000u;
    float lof = v - __uint_as_float(hib);
    hi = (u16)(hib >> 16);
    lo = (u16)(__float_as_uint(lof) >> 16);
}

__device__ __forceinline__ u16 bf16_rtn(float v) {
    u32 b = __float_as_uint(v);
    u32 r = b + 0x7fffu + ((b >> 16) & 1u);
    return (u16)(r >> 16);
}

// ---------------- fwd twiddle tables (dedicated region @ ws+48MiB) ----------
__global__ __launch_bounds__(256) void init_tw(u16* __restrict__ tw) {
    const int tid = blockIdx.x * 256 + threadIdx.x;   // 0..32767
    const float TWO_PI = 6.28318530717958647692f;
    if (tid < 16384) {
        const int e = tid & 7, lane = (tid >> 3) & 63;
        const int nt = (tid >> 9) & 3, kc = tid >> 11;
        const int w = kc * 32 + (lane >> 4) * 8 + e;
        const int n = nt * 16 + (lane & 15);
        const int kx = n >> 1, p = n & 1;
        const float ang = TWO_PI * (float)((kx * w) & 255) * INV256;
        const float v = p ? -sinf(ang) : cosf(ang);
        u16 hi, lo; bf16_split(v, hi, lo);
        tw[tid] = hi; tw[16384 + tid] = lo;
    } else {
        const int u = tid - 16384;
        const int e = u & 7, lane = (u >> 3) & 63;
        const int kc = (u >> 9) & 7, mt = u >> 12;
        const int m = mt * 16 + (lane & 15);
        const int h = kc * 32 + (lane >> 4) * 8 + e;
        const int ky = (m < 32) ? m : (192 + m);
        const float ang = TWO_PI * (float)((ky * h) & 255) * INV256;
        const float c = cosf(ang), s = sinf(ang);
        u16 hi, lo;
        bf16_split(c,  hi, lo); tw[32768 + u] = hi; tw[49152 + u]  = lo;
        bf16_split(s,  hi, lo); tw[65536 + u] = hi; tw[81920 + u]  = lo;
        bf16_split(-s, hi, lo); tw[98304 + u] = hi; tw[114688 + u] = lo;
    }
}

// ---------------- inv twiddle tables ----------------------------------------
__global__ __launch_bounds__(256) void init_tw2(u16* __restrict__ tw2) {
    const int tid = blockIdx.x * 256 + threadIdx.x;   // 0..32767
    const float TWO_PI = 6.28318530717958647692f;
    if (tid < 16384) {
        const int e = tid & 7, lane = (tid >> 3) & 63;
        const int kc = (tid >> 9) & 1, HT = tid >> 10;
        const int h = HT * 16 + (lane & 15);
        const int m = kc * 32 + ((lane >> 4) << 3) + e;
        const int ky = (m < 32) ? m : (192 + m);
        const float ang = TWO_PI * (float)((ky * h) & 255) * INV256;
        tw2[tid]         = bf16_rtn(cosf(ang));
        tw2[16384 + tid] = bf16_rtn(sinf(ang));
        tw2[32768 + tid] = bf16_rtn(-sinf(ang));
    } else {
        const int u = tid - 16384;
        const int e = u & 7, lane = (u >> 3) & 63;
        const int kc = (u >> 9) & 1, nt = u >> 10;
        const int w = nt * 16 + (lane & 15);
        const int kk = kc * 32 + ((lane >> 4) << 3) + e;
        const int kx = kk >> 1, c = kk & 1;
        const float wt = (kx == 0) ? 1.f : 2.f;
        const float ang = TWO_PI * (float)((kx * w) & 255) * INV256;
        const float v = c ? (-wt * sinf(ang) * INV256) : (wt * cosf(ang) * INV256);
        tw2[49152 + u] = bf16_rtn(v);
    }
}

// ---------------- Kernel 1: forward partial rfft2 via MFMA ----------------
__global__ __launch_bounds__(256) void fwd_mfma(const float* __restrict__ x,
                                                const u16* __restrict__ tw,
                                                float2* __restrict__ xft) {
    __shared__ u16 planes[4 * 32 * 264];   // 67584 B
    const int t = threadIdx.x;
    const int lane = t & 63;
    const int wv = t >> 6;
    const int l15 = lane & 15;
    const int lk = lane >> 4;
    const float* __restrict__ xb = x + (size_t)blockIdx.x * (NH * NW);

    const u16* __restrict__ T1h = tw;
    const u16* __restrict__ T1l = tw + 16384;

    for (int mt = 0; mt < 4; ++mt) {
        const int hbase = wv * 64 + mt * 16;
        f32x4 acc[4] = {f32x4{0,0,0,0}, f32x4{0,0,0,0}, f32x4{0,0,0,0}, f32x4{0,0,0,0}};
        for (int kc = 0; kc < 8; ++kc) {
            const float* xr = xb + (size_t)(hbase + l15) * NW + kc * 32 + lk * 8;
            const float4 xa = *(const float4*)xr;
            const float4 xc = *(const float4*)(xr + 4);
            const float v[8] = {xa.x, xa.y, xa.z, xa.w, xc.x, xc.y, xc.z, xc.w};
            short8v Ah, Al;
            #pragma unroll
            for (int e = 0; e < 8; ++e) {
                u16 hi, lo; bf16_split(v[e], hi, lo);
                Ah[e] = (short)hi; Al[e] = (short)lo;
            }
            const int tbase = (kc * 4) * 512 + lane * 8;
            #pragma unroll
            for (int nt = 0; nt < 4; ++nt) {
                const short8v Bh = *(const short8v*)(T1h + tbase + nt * 512);
                const short8v Bl = *(const short8v*)(T1l + tbase + nt * 512);
                acc[nt] = __builtin_amdgcn_mfma_f32_16x16x32_bf16(Ah, Bh, acc[nt], 0, 0, 0);
                acc[nt] = __builtin_amdgcn_mfma_f32_16x16x32_bf16(Ah, Bl, acc[nt], 0, 0, 0);
                acc[nt] = __builtin_amdgcn_mfma_f32_16x16x32_bf16(Al, Bh, acc[nt], 0, 0, 0);
            }
        }
        #pragma unroll
        for (int nt = 0; nt < 4; ++nt) {
            const int n = nt * 16 + l15;
            const int kx = n >> 1, p = n & 1;
            #pragma unroll
            for (int r = 0; r < 4; ++r) {
                const int h = hbase + lk * 4 + r;
                u16 hi, lo; bf16_split(acc[nt][r], hi, lo);
                planes[(2 * p) * 8448 + kx * 264 + h] = hi;
                planes[(2 * p + 1) * 8448 + kx * 264 + h] = lo;
            }
        }
    }
    __syncthreads();

    const u16* __restrict__ C2h = tw + 32768;
    const u16* __restrict__ C2l = tw + 49152;
    const u16* __restrict__ S2h = tw + 65536;
    const u16* __restrict__ S2l = tw + 81920;
    const u16* __restrict__ Snh = tw + 98304;
    const u16* __restrict__ Snl = tw + 114688;

    f32x4 zre[2] = {f32x4{0,0,0,0}, f32x4{0,0,0,0}};
    f32x4 zim[2] = {f32x4{0,0,0,0}, f32x4{0,0,0,0}};
    for (int kc = 0; kc < 8; ++kc) {
        const int abase = (wv * 8 + kc) * 512 + lane * 8;
        const short8v Ch = *(const short8v*)(C2h + abase);
        const short8v Cl = *(const short8v*)(C2l + abase);
        const short8v Sh = *(const short8v*)(S2h + abase);
        const short8v Sl = *(const short8v*)(S2l + abase);
        const short8v Nh = *(const short8v*)(Snh + abase);
        const short8v Nl = *(const short8v*)(Snl + abase);
        #pragma unroll
        for (int nt = 0; nt < 2; ++nt) {
            const int kx = nt * 16 + l15;
            const int off = kx * 264 + kc * 32 + lk * 8;
            const short8v Yrh = *(const short8v*)(planes + off);
            const short8v Yrl = *(const short8v*)(planes + 8448 + off);
            const short8v Yih = *(const short8v*)(planes + 16896 + off);
            const short8v Yil = *(const short8v*)(planes + 25344 + off);
            zre[nt] = __builtin_amdgcn_mfma_f32_16x16x32_bf16(Ch, Yrh, zre[nt], 0, 0, 0);
            zre[nt] = __builtin_amdgcn_mfma_f32_16x16x32_bf16(Ch, Yrl, zre[nt], 0, 0, 0);
            zre[nt] = __builtin_amdgcn_mfma_f32_16x16x32_bf16(Cl, Yrh, zre[nt], 0, 0, 0);
            zre[nt] = __builtin_amdgcn_mfma_f32_16x16x32_bf16(Sh, Yih, zre[nt], 0, 0, 0);
            zre[nt] = __builtin_amdgcn_mfma_f32_16x16x32_bf16(Sh, Yil, zre[nt], 0, 0, 0);
            zre[nt] = __builtin_amdgcn_mfma_f32_16x16x32_bf16(Sl, Yih, zre[nt], 0, 0, 0);
            zim[nt] = __builtin_amdgcn_mfma_f32_16x16x32_bf16(Ch, Yih, zim[nt], 0, 0, 0);
            zim[nt] = __builtin_amdgcn_mfma_f32_16x16x32_bf16(Ch, Yil, zim[nt], 0, 0, 0);
            zim[nt] = __builtin_amdgcn_mfma_f32_16x16x32_bf16(Cl, Yih, zim[nt], 0, 0, 0);
            zim[nt] = __builtin_amdgcn_mfma_f32_16x16x32_bf16(Nh, Yrh, zim[nt], 0, 0, 0);
            zim[nt] = __builtin_amdgcn_mfma_f32_16x16x32_bf16(Nh, Yrl, zim[nt], 0, 0, 0);
            zim[nt] = __builtin_amdgcn_mfma_f32_16x16x32_bf16(Nl, Yrh, zim[nt], 0, 0, 0);
        }
    }
    float2* __restrict__ op = xft + (size_t)blockIdx.x * (NM * NKX);
    #pragma unroll
    for (int nt = 0; nt < 2; ++nt) {
        const int kx = nt * 16 + l15;
        #pragma unroll
        for (int r = 0; r < 4; ++r) {
            const int m = wv * 16 + lk * 4 + r;
            op[m * NKX + kx] = make_float2(zre[nt][r] * INV256, zim[nt][r] * INV256);
        }
    }
}

// ---------------- Kernel 2: per-mode channel contraction (v9) ----------------
// grid = (m=64, og=4, kh=4), 256 threads. BIG-BURST double-buffered phases:
// 4 phases x 16 i. ALL 256 threads load 8x16B per phase (64B islands, 4
// consecutive lanes per island -> full line use; 32KB/block in flight).
// Compute window = 512 FMA/thread (~1-2k cyc) covers HBM latency. 4 barriers,
// no loads outstanding at any barrier. FMA order identical to v3.
__global__ __launch_bounds__(256) void mode_v9(const float2* __restrict__ xft,
                                               const int* __restrict__ q1,
                                               const int* __restrict__ q2,
                                               const float* __restrict__ w1s,
                                               const float* __restrict__ w1m,
                                               const float* __restrict__ w2s,
                                               const float* __restrict__ w2m,
                                               float2* __restrict__ oft) {
    __shared__ float2 xs[2][16][16][8];     // [buf][il][b][k]     32768 B
    __shared__ float2 ws[2][16][16][9];     // [buf][il][o][k+pad] 36864 B (69.6KB tot)
    const int m  = blockIdx.x;              // 0..63
    const int og = blockIdx.y;              // 0..3
    const int kh = blockIdx.z;              // 0..3
    const int t = threadIdx.x;
    const int b = t >> 4, o = t & 15;
    const int mm = (m < 32) ? m : (m - 32);
    const int* __restrict__ q = (m < 32) ? q1 : q2;
    const float scale = (m < 32) ? w1s[0] : w2s[0];
    const float wmin  = (m < 32) ? w1m[0] : w2m[0];

    // loader role: quarter q4 = t&3 (16B within a 64B island), row r = t>>2
    // (0..63); 4 passes cover 256 rows/phase. row = il*16 + rr.
    const int q4 = t & 3;
    const int r0 = t >> 2;                  // 0..63

    const float4* __restrict__ xf4 = (const float4*)xft;
    const int4*   __restrict__ qi4 = (const int4*)q;

    float4 lx0, lx1, lx2, lx3; int4 lw0, lw1, lw2, lw3;

    // row -> (il, rb): il = row>>4, rb = row&15. i = p*16 + il.
    // x f4 addr: (rb*64 + i)*1024 + m*16 + kh*4 + q4
    // w i4 addr: (i*64 + og*16 + ro)*512 + mm*16 + kh*4 + q4
    #define MV9_LOAD(P)                                                        \
        {                                                                      \
            const int row0 = r0,      il0_ = row0 >> 4, rb0_ = row0 & 15;      \
            const int row1 = r0 + 64, il1_ = row1 >> 4, rb1_ = row1 & 15;      \
            const int row2 = r0 + 128,il2_ = row2 >> 4, rb2_ = row2 & 15;      \
            const int row3 = r0 + 192,il3_ = row3 >> 4, rb3_ = row3 & 15;      \
            lx0 = xf4[(size_t)(rb0_ * 64 + (P) * 16 + il0_) * 1024 + m * 16 + kh * 4 + q4]; \
            lx1 = xf4[(size_t)(rb1_ * 64 + (P) * 16 + il1_) * 1024 + m * 16 + kh * 4 + q4]; \
            lx2 = xf4[(size_t)(rb2_ * 64 + (P) * 16 + il2_) * 1024 + m * 16 + kh * 4 + q4]; \
            lx3 = xf4[(size_t)(rb3_ * 64 + (P) * 16 + il3_) * 1024 + m * 16 + kh * 4 + q4]; \
            lw0 = qi4[(size_t)(((P) * 16 + il0_) * 64 + og * 16 + rb0_) * 512 + mm * 16 + kh * 4 + q4]; \
            lw1 = qi4[(size_t)(((P) * 16 + il1_) * 64 + og * 16 + rb1_) * 512 + mm * 16 + kh * 4 + q4]; \
            lw2 = qi4[(size_t)(((P) * 16 + il2_) * 64 + og * 16 + rb2_) * 512 + mm * 16 + kh * 4 + q4]; \
            lw3 = qi4[(size_t)(((P) * 16 + il3_) * 64 + og * 16 + rb3_) * 512 + mm * 16 + kh * 4 + q4]; \
        }

    #define MV9_DEQ(LW) make_float4(((float)(LW).x + 127.f) * scale + wmin,    \
                                    ((float)(LW).y + 127.f) * scale + wmin,    \
                                    ((float)(LW).z + 127.f) * scale + wmin,    \
                                    ((float)(LW).w + 127.f) * scale + wmin)

    #define MV9_WRITE(BUF)                                                     \
        {                                                                      \
            const int row0 = r0,      il0_ = row0 >> 4, rb0_ = row0 & 15;      \
            const int row1 = r0 + 64, il1_ = row1 >> 4, rb1_ = row1 & 15;      \
            const int row2 = r0 + 128,il2_ = row2 >> 4, rb2_ = row2 & 15;      \
            const int row3 = r0 + 192,il3_ = row3 >> 4, rb3_ = row3 & 15;      \
            *(float4*)&xs[BUF][il0_][rb0_][q4 * 2] = lx0;                      \
            *(float4*)&xs[BUF][il1_][rb1_][q4 * 2] = lx1;                      \
            *(float4*)&xs[BUF][il2_][rb2_][q4 * 2] = lx2;                      \
            *(float4*)&xs[BUF][il3_][rb3_][q4 * 2] = lx3;                      \
            *(float4*)&ws[BUF][il0_][rb0_][q4 * 2] = MV9_DEQ(lw0);             \
            *(float4*)&ws[BUF][il1_][rb1_][q4 * 2] = MV9_DEQ(lw1);             \
            *(float4*)&ws[BUF][il2_][rb2_][q4 * 2] = MV9_DEQ(lw2);             \
            *(float4*)&ws[BUF][il3_][rb3_][q4 * 2] = MV9_DEQ(lw3);             \
        }

    // prologue
    MV9_LOAD(0)
    MV9_WRITE(0)
    __syncthreads();

    float accr[8], acci[8];
    #pragma unroll
    for (int k = 0; k < 8; ++k) { accr[k] = 0.f; acci[k] = 0.f; }

    #pragma unroll 1
    for (int p = 0; p < 4; ++p) {
        const int cur = p & 1;
        if (p < 3) { MV9_LOAD(p + 1) }
        #pragma unroll
        for (int jl = 0; jl < 16; ++jl) {
            const float4* xr4 = (const float4*)&xs[cur][jl][b][0];
            const float4* wr4 = (const float4*)&ws[cur][jl][o][0];
            #pragma unroll
            for (int kq = 0; kq < 4; ++kq) {
                const float4 xv = xr4[kq];
                const float4 wv = wr4[kq];
                accr[2 * kq]     += xv.x * wv.x - xv.y * wv.y;
                acci[2 * kq]     += xv.x * wv.y + xv.y * wv.x;
                accr[2 * kq + 1] += xv.z * wv.z - xv.w * wv.w;
                acci[2 * kq + 1] += xv.z * wv.w + xv.w * wv.z;
            }
        }
        if (p < 3) {
            MV9_WRITE(cur ^ 1)
            __syncthreads();
        }
    }
    #undef MV9_LOAD
    #undef MV9_DEQ
    #undef MV9_WRITE

    float2* __restrict__ op = oft + ((size_t)(b * 64 + og * 16 + o) * NM + m) * NKX + kh * 8;
    #pragma unroll
    for (int k = 0; k < 8; ++k) op[k] = make_float2(accr[k], acci[k]);
}

// ---------------- Kernel 3: inverse partial irfft2 via MFMA (round-5) -------
// grid = (B*COUT, 2), 256 threads (4 waves). Block handles 128 h rows.
__global__ __launch_bounds__(256) void inv_mfma(const float2* __restrict__ oft,
                                                const u16* __restrict__ tw2,
                                                float* __restrict__ out) {
    __shared__ u16 lds[13824];   // 27648 B -> 5 blocks/CU
    const int t = threadIdx.x;
    const int lane = t & 63;
    const int wv = t >> 6;
    const int l15 = lane & 15;
    const int lk = lane >> 4;
    const int hh = blockIdx.y;   // 0/1: h half

    const float2* __restrict__ ip = oft + (size_t)blockIdx.x * (NM * NKX);
    #pragma unroll
    for (int r = 0; r < 8; ++r) {
        const int idx = r * 256 + t;
        const int m = idx >> 5, kx = idx & 31;
        const float2 v = ip[idx];
        lds[kx * 72 + m]        = bf16_rtn(v.x);
        lds[2304 + kx * 72 + m] = bf16_rtn(v.y);
    }
    __syncthreads();

    const u16* __restrict__ C4 = tw2;
    const u16* __restrict__ S4 = tw2 + 16384;
    const u16* __restrict__ N4 = tw2 + 32768;

    short8v Br[2][2], Bi[2][2];
    #pragma unroll
    for (int nt = 0; nt < 2; ++nt) {
        #pragma unroll
        for (int kc = 0; kc < 2; ++kc) {
            const int off = (nt * 16 + l15) * 72 + kc * 32 + lk * 8;
            Br[nt][kc] = *(const short8v*)(lds + off);
            Bi[nt][kc] = *(const short8v*)(lds + 2304 + off);
        }
    }

    #pragma unroll
    for (int mt = 0; mt < 2; ++mt) {
        const int lt = wv * 2 + mt;       // local 16-row tile 0..7
        const int HT = hh * 8 + lt;       // global tile 0..15
        f32x4 zr[2] = {f32x4{0,0,0,0}, f32x4{0,0,0,0}};
        f32x4 zi[2] = {f32x4{0,0,0,0}, f32x4{0,0,0,0}};
        #pragma unroll
        for (int kc = 0; kc < 2; ++kc) {
            const int abase = ((HT * 2 + kc) * 64 + lane) * 8;
            const short8v C = *(const short8v*)(C4 + abase);
            const short8v S = *(const short8v*)(S4 + abase);
            const short8v N = *(const short8v*)(N4 + abase);
            #pragma unroll
            for (int nt = 0; nt < 2; ++nt) {
                zr[nt] = __builtin_amdgcn_mfma_f32_16x16x32_bf16(C, Br[nt][kc], zr[nt], 0, 0, 0);
                zr[nt] = __builtin_amdgcn_mfma_f32_16x16x32_bf16(N, Bi[nt][kc], zr[nt], 0, 0, 0);
                zi[nt] = __builtin_amdgcn_mfma_f32_16x16x32_bf16(S, Br[nt][kc], zi[nt], 0, 0, 0);
                zi[nt] = __builtin_amdgcn_mfma_f32_16x16x32_bf16(C, Bi[nt][kc], zi[nt], 0, 0, 0);
            }
        }
        #pragma unroll
        for (int nt = 0; nt < 2; ++nt) {
            const int kx = nt * 16 + l15;
            #pragma unroll
            for (int r = 0; r < 4; ++r) {
                const int hl = lt * 16 + lk * 4 + r;
                const u32 pk = (u32)bf16_rtn(zr[nt][r]) | ((u32)bf16_rtn(zi[nt][r]) << 16);
                *(u32*)(lds + 4608 + hl * 72 + 2 * kx) = pk;
            }
        }
    }
    __syncthreads();

    const u16* __restrict__ W5 = tw2 + 49152;
    float* __restrict__ op = out + (size_t)blockIdx.x * (NH * NW) + (size_t)hh * 128 * NW;
    for (int nt = 0; nt < 16; ++nt) {
        const short8v B0 = *(const short8v*)(W5 + ((nt * 2 + 0) * 64 + lane) * 8);
        const short8v B1 = *(const short8v*)(W5 + ((nt * 2 + 1) * 64 + lane) * 8);
        const int w = nt * 16 + l15;
        #pragma unroll
        for (int mt = 0; mt < 2; ++mt) {
            const int lt = wv * 2 + mt;
            const int h0 = lt * 16 + l15;
            const short8v A0 = *(const short8v*)(lds + 4608 + h0 * 72 + lk * 8);
            const short8v A1 = *(const short8v*)(lds + 4608 + h0 * 72 + 32 + lk * 8);
            f32x4 acc = {0, 0, 0, 0};
            acc = __builtin_amdgcn_mfma_f32_16x16x32_bf16(A0, B0, acc, 0, 0, 0);
            acc = __builtin_amdgcn_mfma_f32_16x16x32_bf16(A1, B1, acc, 0, 0, 0);
            #pragma unroll
            for (int r = 0; r < 4; ++r) {
                const int hl = lt * 16 + lk * 4 + r;
                op[hl * 256 + w] = acc[r];
            }
        }
    }
}

extern "C" void kernel_launch(void* const* d_in, const int* in_sizes, int n_in,
                              void* d_out, int out_size, void* d_ws, size_t ws_size,
                              hipStream_t stream) {
    const float* x  = (const float*)d_in[0];
    const int* q1   = (const int*)d_in[1];
    const int* q2   = (const int*)d_in[2];
    const float* w1s = (const float*)d_in[3];
    const float* w1m = (const float*)d_in[4];
    const float* w2s = (const float*)d_in[5];
    const float* w2m = (const float*)d_in[6];
    float* out = (float*)d_out;

    float2* xft = (float2*)d_ws;                          // [0, 16 MiB)
    float2* oft = xft + (size_t)NB * NCIN * NM * NKX;     // [16, 32 MiB)
    u16* tw  = (u16*)((char*)d_ws + (size_t)48 * 1024 * 1024);  // 256 KiB
    u16* tw2 = tw + 131072;                                      // 128 KiB

    init_tw<<<128, 256, 0, stream>>>(tw);
    init_tw2<<<128, 256, 0, stream>>>(tw2);
    fwd_mfma<<<NB * NCIN, 256, 0, stream>>>(x, tw, xft);
    mode_v9<<<dim3(NM, 4, 4), 256, 0, stream>>>(xft, q1, q2, w1s, w1m, w2s, w2m, oft);
    inv_mfma<<<dim3(NB * NCOUT, 2), 256, 0, stream>>>(oft, tw2, out);
}

// Round 13
// 237.152 us; speedup vs baseline: 1.9173x; 1.9173x over previous
//
#include <hip/hip_runtime.h>
#include <math.h>

#define NB 16
#define NCIN 64
#define NCOUT 64
#define NH 256
#define NW 256
#define NM 64          // 2*M1 row modes
#define NKX 32         // M2 retained columns
#define INV256 (1.0f/256.0f)

typedef __attribute__((ext_vector_type(8))) short short8v;
typedef __attribute__((ext_vector_type(4))) float f32x4;
typedef unsigned short u16;
typedef unsigned int u32;

__device__ __forceinline__ void bf16_split(float v, u16& hi, u16& lo) {
    u32 b = __float_as_uint(v);
    u32 hib = b & 0xffff0000u;
    float lof = v - __uint_as_float(hib);
    hi = (u16)(hib >> 16);
    lo = (u16)(__float_as_uint(lof) >> 16);
}

__device__ __forceinline__ u16 bf16_rtn(float v) {
    u32 b = __float_as_uint(v);
    u32 r = b + 0x7fffu + ((b >> 16) & 1u);
    return (u16)(r >> 16);
}

// ---------------- fwd twiddle tables (dedicated region @ ws+48MiB) ----------
__global__ __launch_bounds__(256) void init_tw(u16* __restrict__ tw) {
    const int tid = blockIdx.x * 256 + threadIdx.x;   // 0..32767
    const float TWO_PI = 6.28318530717958647692f;
    if (tid < 16384) {
        const int e = tid & 7, lane = (tid >> 3) & 63;
        const int nt = (tid >> 9) & 3, kc = tid >> 11;
        const int w = kc * 32 + (lane >> 4) * 8 + e;
        const int n = nt * 16 + (lane & 15);
        const int kx = n >> 1, p = n & 1;
        const float ang = TWO_PI * (float)((kx * w) & 255) * INV256;
        const float v = p ? -sinf(ang) : cosf(ang);
        u16 hi, lo; bf16_split(v, hi, lo);
        tw[tid] = hi; tw[16384 + tid] = lo;
    } else {
        const int u = tid - 16384;
        const int e = u & 7, lane = (u >> 3) & 63;
        const int kc = (u >> 9) & 7, mt = u >> 12;
        const int m = mt * 16 + (lane & 15);
        const int h = kc * 32 + (lane >> 4) * 8 + e;
        const int ky = (m < 32) ? m : (192 + m);
        const float ang = TWO_PI * (float)((ky * h) & 255) * INV256;
        const float c = cosf(ang), s = sinf(ang);
        u16 hi, lo;
        bf16_split(c,  hi, lo); tw[32768 + u] = hi; tw[49152 + u]  = lo;
        bf16_split(s,  hi, lo); tw[65536 + u] = hi; tw[81920 + u]  = lo;
        bf16_split(-s, hi, lo); tw[98304 + u] = hi; tw[114688 + u] = lo;
    }
}

// ---------------- inv twiddle tables ----------------------------------------
__global__ __launch_bounds__(256) void init_tw2(u16* __restrict__ tw2) {
    const int tid = blockIdx.x * 256 + threadIdx.x;   // 0..32767
    const float TWO_PI = 6.28318530717958647692f;
    if (tid < 16384) {
        const int e = tid & 7, lane = (tid >> 3) & 63;
        const int kc = (tid >> 9) & 1, HT = tid >> 10;
        const int h = HT * 16 + (lane & 15);
        const int m = kc * 32 + ((lane >> 4) << 3) + e;
        const int ky = (m < 32) ? m : (192 + m);
        const float ang = TWO_PI * (float)((ky * h) & 255) * INV256;
        tw2[tid]         = bf16_rtn(cosf(ang));
        tw2[16384 + tid] = bf16_rtn(sinf(ang));
        tw2[32768 + tid] = bf16_rtn(-sinf(ang));
    } else {
        const int u = tid - 16384;
        const int e = u & 7, lane = (u >> 3) & 63;
        const int kc = (u >> 9) & 1, nt = u >> 10;
        const int w = nt * 16 + (lane & 15);
        const int kk = kc * 32 + ((lane >> 4) << 3) + e;
        const int kx = kk >> 1, c = kk & 1;
        const float wt = (kx == 0) ? 1.f : 2.f;
        const float ang = TWO_PI * (float)((kx * w) & 255) * INV256;
        const float v = c ? (-wt * sinf(ang) * INV256) : (wt * cosf(ang) * INV256);
        tw2[49152 + u] = bf16_rtn(v);
    }
}

// ---------------- Kernel 1: forward partial rfft2 via MFMA ----------------
__global__ __launch_bounds__(256) void fwd_mfma(const float* __restrict__ x,
                                                const u16* __restrict__ tw,
                                                float2* __restrict__ xft) {
    __shared__ u16 planes[4 * 32 * 264];   // 67584 B
    const int t = threadIdx.x;
    const int lane = t & 63;
    const int wv = t >> 6;
    const int l15 = lane & 15;
    const int lk = lane >> 4;
    const float* __restrict__ xb = x + (size_t)blockIdx.x * (NH * NW);

    const u16* __restrict__ T1h = tw;
    const u16* __restrict__ T1l = tw + 16384;

    for (int mt = 0; mt < 4; ++mt) {
        const int hbase = wv * 64 + mt * 16;
        f32x4 acc[4] = {f32x4{0,0,0,0}, f32x4{0,0,0,0}, f32x4{0,0,0,0}, f32x4{0,0,0,0}};
        for (int kc = 0; kc < 8; ++kc) {
            const float* xr = xb + (size_t)(hbase + l15) * NW + kc * 32 + lk * 8;
            const float4 xa = *(const float4*)xr;
            const float4 xc = *(const float4*)(xr + 4);
            const float v[8] = {xa.x, xa.y, xa.z, xa.w, xc.x, xc.y, xc.z, xc.w};
            short8v Ah, Al;
            #pragma unroll
            for (int e = 0; e < 8; ++e) {
                u16 hi, lo; bf16_split(v[e], hi, lo);
                Ah[e] = (short)hi; Al[e] = (short)lo;
            }
            const int tbase = (kc * 4) * 512 + lane * 8;
            #pragma unroll
            for (int nt = 0; nt < 4; ++nt) {
                const short8v Bh = *(const short8v*)(T1h + tbase + nt * 512);
                const short8v Bl = *(const short8v*)(T1l + tbase + nt * 512);
                acc[nt] = __builtin_amdgcn_mfma_f32_16x16x32_bf16(Ah, Bh, acc[nt], 0, 0, 0);
                acc[nt] = __builtin_amdgcn_mfma_f32_16x16x32_bf16(Ah, Bl, acc[nt], 0, 0, 0);
                acc[nt] = __builtin_amdgcn_mfma_f32_16x16x32_bf16(Al, Bh, acc[nt], 0, 0, 0);
            }
        }
        #pragma unroll
        for (int nt = 0; nt < 4; ++nt) {
            const int n = nt * 16 + l15;
            const int kx = n >> 1, p = n & 1;
            #pragma unroll
            for (int r = 0; r < 4; ++r) {
                const int h = hbase + lk * 4 + r;
                u16 hi, lo; bf16_split(acc[nt][r], hi, lo);
                planes[(2 * p) * 8448 + kx * 264 + h] = hi;
                planes[(2 * p + 1) * 8448 + kx * 264 + h] = lo;
            }
        }
    }
    __syncthreads();

    const u16* __restrict__ C2h = tw + 32768;
    const u16* __restrict__ C2l = tw + 49152;
    const u16* __restrict__ S2h = tw + 65536;
    const u16* __restrict__ S2l = tw + 81920;
    const u16* __restrict__ Snh = tw + 98304;
    const u16* __restrict__ Snl = tw + 114688;

    f32x4 zre[2] = {f32x4{0,0,0,0}, f32x4{0,0,0,0}};
    f32x4 zim[2] = {f32x4{0,0,0,0}, f32x4{0,0,0,0}};
    for (int kc = 0; kc < 8; ++kc) {
        const int abase = (wv * 8 + kc) * 512 + lane * 8;
        const short8v Ch = *(const short8v*)(C2h + abase);
        const short8v Cl = *(const short8v*)(C2l + abase);
        const short8v Sh = *(const short8v*)(S2h + abase);
        const short8v Sl = *(const short8v*)(S2l + abase);
        const short8v Nh = *(const short8v*)(Snh + abase);
        const short8v Nl = *(const short8v*)(Snl + abase);
        #pragma unroll
        for (int nt = 0; nt < 2; ++nt) {
            const int kx = nt * 16 + l15;
            const int off = kx * 264 + kc * 32 + lk * 8;
            const short8v Yrh = *(const short8v*)(planes + off);
            const short8v Yrl = *(const short8v*)(planes + 8448 + off);
            const short8v Yih = *(const short8v*)(planes + 16896 + off);
            const short8v Yil = *(const short8v*)(planes + 25344 + off);
            zre[nt] = __builtin_amdgcn_mfma_f32_16x16x32_bf16(Ch, Yrh, zre[nt], 0, 0, 0);
            zre[nt] = __builtin_amdgcn_mfma_f32_16x16x32_bf16(Ch, Yrl, zre[nt], 0, 0, 0);
            zre[nt] = __builtin_amdgcn_mfma_f32_16x16x32_bf16(Cl, Yrh, zre[nt], 0, 0, 0);
            zre[nt] = __builtin_amdgcn_mfma_f32_16x16x32_bf16(Sh, Yih, zre[nt], 0, 0, 0);
            zre[nt] = __builtin_amdgcn_mfma_f32_16x16x32_bf16(Sh, Yil, zre[nt], 0, 0, 0);
            zre[nt] = __builtin_amdgcn_mfma_f32_16x16x32_bf16(Sl, Yih, zre[nt], 0, 0, 0);
            zim[nt] = __builtin_amdgcn_mfma_f32_16x16x32_bf16(Ch, Yih, zim[nt], 0, 0, 0);
            zim[nt] = __builtin_amdgcn_mfma_f32_16x16x32_bf16(Ch, Yil, zim[nt], 0, 0, 0);
            zim[nt] = __builtin_amdgcn_mfma_f32_16x16x32_bf16(Cl, Yih, zim[nt], 0, 0, 0);
            zim[nt] = __builtin_amdgcn_mfma_f32_16x16x32_bf16(Nh, Yrh, zim[nt], 0, 0, 0);
            zim[nt] = __builtin_amdgcn_mfma_f32_16x16x32_bf16(Nh, Yrl, zim[nt], 0, 0, 0);
            zim[nt] = __builtin_amdgcn_mfma_f32_16x16x32_bf16(Nl, Yrh, zim[nt], 0, 0, 0);
        }
    }
    float2* __restrict__ op = xft + (size_t)blockIdx.x * (NM * NKX);
    #pragma unroll
    for (int nt = 0; nt < 2; ++nt) {
        const int kx = nt * 16 + l15;
        #pragma unroll
        for (int r = 0; r < 4; ++r) {
            const int m = wv * 16 + lk * 4 + r;
            op[m * NKX + kx] = make_float2(zre[nt][r] * INV256, zim[nt][r] * INV256);
        }
    }
}

// ---------------- Kernel 2: per-mode channel contraction (v10) ---------------
// grid = (m=64, og=8, kh=8), 256 threads. BARRIER-FREE steady state:
// stage the block's ENTIRE weight slab once (16KB f32 after dequant, deep-MLP
// int4 burst), one __syncthreads, then a barrier-free i-loop: each thread
// streams its own x (float4, batched 8-deep) + conflict-free ds_read_b128 of
// w. No LDS writes / barriers in the loop -> no vmcnt(0) drains; prefetch
// depth is set by the unrolled load batch, not by barrier spacing.
// Thread (b=t>>4, ol=(t>>1)&7, kp=t&1) owns (b, o=og*8+ol, kx=kh*4+kp*2..+1).
// Dequant expr and i-ascending FMA order identical to v3 -> bit-identical.
__global__ __launch_bounds__(256) void mode_v10(const float2* __restrict__ xft,
                                                const int* __restrict__ q1,
                                                const int* __restrict__ q2,
                                                const float* __restrict__ w1s,
                                                const float* __restrict__ w1m,
                                                const float* __restrict__ w2s,
                                                const float* __restrict__ w2m,
                                                float2* __restrict__ oft) {
    __shared__ float wlds[4096];            // [i64][ol8][kxl4][c2] f32 = 16 KB
    const int m  = blockIdx.x;              // 0..63
    const int og = blockIdx.y;              // 0..7
    const int kh = blockIdx.z;              // 0..7
    const int t = threadIdx.x;
    const int mm = (m < 32) ? m : (m - 32);
    const int* __restrict__ q = (m < 32) ? q1 : q2;
    const float scale = (m < 32) ? w1s[0] : w2s[0];
    const float wmin  = (m < 32) ? w1m[0] : w2m[0];

    // ---- stage weights: rows 2t, 2t+1; each row = (i, ol) -> 8 int32 (32B)
    {
        const int4* __restrict__ qi4 = (const int4*)q;
        int4 v[4];
        #pragma unroll
        for (int rr = 0; rr < 2; ++rr) {
            const int row = t * 2 + rr;         // 0..511
            const int i = row >> 3, ol = row & 7;
            // int32 idx = (((i*64 + og*8+ol)*32 + mm)*32 + kh*4)*2 ; /4 -> int4
            const size_t b4 = (size_t)(i * 64 + og * 8 + ol) * 512 + mm * 16 + kh * 2;
            v[rr * 2]     = qi4[b4];
            v[rr * 2 + 1] = qi4[b4 + 1];
        }
        #pragma unroll
        for (int rr = 0; rr < 2; ++rr) {
            const int row = t * 2 + rr;
            float* wd = &wlds[row * 8];
            const int4 a = v[rr * 2], bq = v[rr * 2 + 1];
            wd[0] = ((float)a.x + 127.f) * scale + wmin;
            wd[1] = ((float)a.y + 127.f) * scale + wmin;
            wd[2] = ((float)a.z + 127.f) * scale + wmin;
            wd[3] = ((float)a.w + 127.f) * scale + wmin;
            wd[4] = ((float)bq.x + 127.f) * scale + wmin;
            wd[5] = ((float)bq.y + 127.f) * scale + wmin;
            wd[6] = ((float)bq.z + 127.f) * scale + wmin;
            wd[7] = ((float)bq.w + 127.f) * scale + wmin;
        }
    }
    __syncthreads();

    // ---- barrier-free i-loop ----
    const int b  = t >> 4;
    const int ol = (t >> 1) & 7;
    const int kp = t & 1;
    const float4* __restrict__ xf4 = (const float4*)xft;
    const size_t xoff = (size_t)m * 16 + kh * 2 + kp;   // within (b,i) row of 1024 f4

    float accr0 = 0.f, acci0 = 0.f, accr1 = 0.f, acci1 = 0.f;

    #pragma unroll 1
    for (int i0 = 0; i0 < 64; i0 += 8) {
        float4 xb[8];
        #pragma unroll
        for (int u = 0; u < 8; ++u)
            xb[u] = xf4[(size_t)(b * 64 + i0 + u) * 1024 + xoff];
        #pragma unroll
        for (int u = 0; u < 8; ++u) {
            const float4 wv = *(const float4*)&wlds[((i0 + u) * 8 + ol) * 8 + kp * 4];
            const float4 xv = xb[u];
            accr0 += xv.x * wv.x - xv.y * wv.y;
            acci0 += xv.x * wv.y + xv.y * wv.x;
            accr1 += xv.z * wv.z - xv.w * wv.w;
            acci1 += xv.z * wv.w + xv.w * wv.z;
        }
    }

    // store: float2 idx = ((b*64 + og*8+ol)*64 + m)*32 + kh*4 + kp*2 -> f4 idx /2
    float4* __restrict__ op4 = (float4*)oft;
    op4[(size_t)((b * 64 + og * 8 + ol) * 64 + m) * 16 + kh * 2 + kp] =
        make_float4(accr0, acci0, accr1, acci1);
}

// ---------------- Kernel 3: inverse partial irfft2 via MFMA (round-5) -------
// grid = (B*COUT, 2), 256 threads (4 waves). Block handles 128 h rows.
__global__ __launch_bounds__(256) void inv_mfma(const float2* __restrict__ oft,
                                                const u16* __restrict__ tw2,
                                                float* __restrict__ out) {
    __shared__ u16 lds[13824];   // 27648 B -> 5 blocks/CU
    const int t = threadIdx.x;
    const int lane = t & 63;
    const int wv = t >> 6;
    const int l15 = lane & 15;
    const int lk = lane >> 4;
    const int hh = blockIdx.y;   // 0/1: h half

    const float2* __restrict__ ip = oft + (size_t)blockIdx.x * (NM * NKX);
    #pragma unroll
    for (int r = 0; r < 8; ++r) {
        const int idx = r * 256 + t;
        const int m = idx >> 5, kx = idx & 31;
        const float2 v = ip[idx];
        lds[kx * 72 + m]        = bf16_rtn(v.x);
        lds[2304 + kx * 72 + m] = bf16_rtn(v.y);
    }
    __syncthreads();

    const u16* __restrict__ C4 = tw2;
    const u16* __restrict__ S4 = tw2 + 16384;
    const u16* __restrict__ N4 = tw2 + 32768;

    short8v Br[2][2], Bi[2][2];
    #pragma unroll
    for (int nt = 0; nt < 2; ++nt) {
        #pragma unroll
        for (int kc = 0; kc < 2; ++kc) {
            const int off = (nt * 16 + l15) * 72 + kc * 32 + lk * 8;
            Br[nt][kc] = *(const short8v*)(lds + off);
            Bi[nt][kc] = *(const short8v*)(lds + 2304 + off);
        }
    }

    #pragma unroll
    for (int mt = 0; mt < 2; ++mt) {
        const int lt = wv * 2 + mt;       // local 16-row tile 0..7
        const int HT = hh * 8 + lt;       // global tile 0..15
        f32x4 zr[2] = {f32x4{0,0,0,0}, f32x4{0,0,0,0}};
        f32x4 zi[2] = {f32x4{0,0,0,0}, f32x4{0,0,0,0}};
        #pragma unroll
        for (int kc = 0; kc < 2; ++kc) {
            const int abase = ((HT * 2 + kc) * 64 + lane) * 8;
            const short8v C = *(const short8v*)(C4 + abase);
            const short8v S = *(const short8v*)(S4 + abase);
            const short8v N = *(const short8v*)(N4 + abase);
            #pragma unroll
            for (int nt = 0; nt < 2; ++nt) {
                zr[nt] = __builtin_amdgcn_mfma_f32_16x16x32_bf16(C, Br[nt][kc], zr[nt], 0, 0, 0);
                zr[nt] = __builtin_amdgcn_mfma_f32_16x16x32_bf16(N, Bi[nt][kc], zr[nt], 0, 0, 0);
                zi[nt] = __builtin_amdgcn_mfma_f32_16x16x32_bf16(S, Br[nt][kc], zi[nt], 0, 0, 0);
                zi[nt] = __builtin_amdgcn_mfma_f32_16x16x32_bf16(C, Bi[nt][kc], zi[nt], 0, 0, 0);
            }
        }
        #pragma unroll
        for (int nt = 0; nt < 2; ++nt) {
            const int kx = nt * 16 + l15;
            #pragma unroll
            for (int r = 0; r < 4; ++r) {
                const int hl = lt * 16 + lk * 4 + r;
                const u32 pk = (u32)bf16_rtn(zr[nt][r]) | ((u32)bf16_rtn(zi[nt][r]) << 16);
                *(u32*)(lds + 4608 + hl * 72 + 2 * kx) = pk;
            }
        }
    }
    __syncthreads();

    const u16* __restrict__ W5 = tw2 + 49152;
    float* __restrict__ op = out + (size_t)blockIdx.x * (NH * NW) + (size_t)hh * 128 * NW;
    for (int nt = 0; nt < 16; ++nt) {
        const short8v B0 = *(const short8v*)(W5 + ((nt * 2 + 0) * 64 + lane) * 8);
        const short8v B1 = *(const short8v*)(W5 + ((nt * 2 + 1) * 64 + lane) * 8);
        const int w = nt * 16 + l15;
        #pragma unroll
        for (int mt = 0; mt < 2; ++mt) {
            const int lt = wv * 2 + mt;
            const int h0 = lt * 16 + l15;
            const short8v A0 = *(const short8v*)(lds + 4608 + h0 * 72 + lk * 8);
            const short8v A1 = *(const short8v*)(lds + 4608 + h0 * 72 + 32 + lk * 8);
            f32x4 acc = {0, 0, 0, 0};
            acc = __builtin_amdgcn_mfma_f32_16x16x32_bf16(A0, B0, acc, 0, 0, 0);
            acc = __builtin_amdgcn_mfma_f32_16x16x32_bf16(A1, B1, acc, 0, 0, 0);
            #pragma unroll
            for (int r = 0; r < 4; ++r) {
                const int hl = lt * 16 + lk * 4 + r;
                op[hl * 256 + w] = acc[r];
            }
        }
    }
}

extern "C" void kernel_launch(void* const* d_in, const int* in_sizes, int n_in,
                              void* d_out, int out_size, void* d_ws, size_t ws_size,
                              hipStream_t stream) {
    const float* x  = (const float*)d_in[0];
    const int* q1   = (const int*)d_in[1];
    const int* q2   = (const int*)d_in[2];
    const float* w1s = (const float*)d_in[3];
    const float* w1m = (const float*)d_in[4];
    const float* w2s = (const float*)d_in[5];
    const float* w2m = (const float*)d_in[6];
    float* out = (float*)d_out;

    float2* xft = (float2*)d_ws;                          // [0, 16 MiB)
    float2* oft = xft + (size_t)NB * NCIN * NM * NKX;     // [16, 32 MiB)
    u16* tw  = (u16*)((char*)d_ws + (size_t)48 * 1024 * 1024);  // 256 KiB
    u16* tw2 = tw + 131072;                                      // 128 KiB

    init_tw<<<128, 256, 0, stream>>>(tw);
    init_tw2<<<128, 256, 0, stream>>>(tw2);
    fwd_mfma<<<NB * NCIN, 256, 0, stream>>>(x, tw, xft);
    mode_v10<<<dim3(NM, 8, 8), 256, 0, stream>>>(xft, q1, q2, w1s, w1m, w2s, w2m, oft);
    inv_mfma<<<dim3(NB * NCOUT, 2), 256, 0, stream>>>(oft, tw2, out);
}